// Round 1
// baseline (589.790 us; speedup 1.0000x reference)
//
#include <hip/hip_runtime.h>
#include <math.h>

#define D 64
#define MIN_NORM 1e-15f
#define PROJ_MAXNORM 0.996f   // (1 - 4e-3) / sqrt(c), c=1

__device__ __forceinline__ float wave_reduce_sum(float v) {
#pragma unroll
    for (int m = 1; m < 64; m <<= 1)
        v += __shfl_xor(v, m, 64);
    return v;
}

__device__ __forceinline__ float artanh_clip(float z) {
    z = fminf(z, 1.0f - 1e-7f);
    z = fmaxf(z, -1.0f + 1e-7f);
    return 0.5f * logf((1.0f + z) / (1.0f - z));
}

// Kernel A: per-node squared norm + logmap0 scale factor; init rowsum to 1e-10.
__global__ void prep_kernel(const float* __restrict__ x,
                            float* __restrict__ sn,
                            float* __restrict__ f,
                            float* __restrict__ rowsum,
                            int N) {
    int node = blockIdx.x * 4 + (threadIdx.x >> 6);
    int lane = threadIdx.x & 63;
    if (node >= N) return;
    float v = x[node * D + lane];
    float s = wave_reduce_sum(v * v);
    if (lane == 0) {
        sn[node] = s;
        float pn = fmaxf(sqrtf(s), MIN_NORM);
        f[node] = artanh_clip(pn) / pn;
        rowsum[node] = 1e-10f;
    }
}

// Kernel B: one wave per edge. Compute hyperbolic attention weight, scatter.
__global__ void edge_kernel(const float* __restrict__ x,
                            const float* __restrict__ sn,
                            const float* __restrict__ f,
                            const int* __restrict__ row_idx,
                            const int* __restrict__ col_idx,
                            const float* __restrict__ beta,
                            const float* __restrict__ con,
                            float* __restrict__ support,
                            float* __restrict__ rowsum,
                            int E) {
    int e = blockIdx.x * 4 + (threadIdx.x >> 6);
    int lane = threadIdx.x & 63;
    if (e >= E) return;
    int r = row_idx[e];
    int c = col_idx[e];
    float xr = x[r * D + lane];
    float xc = x[c * D + lane];
    float d = wave_reduce_sum(xr * xc);   // dot(p1, p2)
    float x2 = sn[r];
    float y2 = sn[c];
    // mobius_add(-p1, p2): num = -a*p1 + b*p2
    float a = 1.0f - 2.0f * d + y2;
    float b = 1.0f - x2;
    float num2 = a * a * x2 - 2.0f * a * b * d + b * b * y2;
    float denom = fmaxf(1.0f - 2.0f * d + x2 * y2, MIN_NORM);
    float man = sqrtf(fmaxf(num2, 0.0f)) / denom;
    float dist = 2.0f * artanh_clip(man);
    float w = expf(-beta[0] * dist * dist + con[0]);
    // x_t[col] = f[col] * x[col]  (reuse loaded xc)
    atomicAdd(&support[r * D + lane], w * f[c] * xc);
    if (lane == 0) atomicAdd(&rowsum[r], w);
}

// Kernel C: in-place finalize: support/rowsum -> expmap0 -> proj
__global__ void final_kernel(float* __restrict__ out,
                             const float* __restrict__ rowsum,
                             int N) {
    int node = blockIdx.x * 4 + (threadIdx.x >> 6);
    int lane = threadIdx.x & 63;
    if (node >= N) return;
    float s = out[node * D + lane] / rowsum[node];  // rowsum already includes 1e-10
    float n2 = wave_reduce_sum(s * s);
    float un = fmaxf(sqrtf(n2), MIN_NORM);
    float t = tanhf(un) / un;   // expmap0 scale
    float o = t * s;
    float on = t * sqrtf(n2);   // ||o||
    if (on > PROJ_MAXNORM)
        o = o / fmaxf(on, MIN_NORM) * PROJ_MAXNORM;
    out[node * D + lane] = o;
}

extern "C" void kernel_launch(void* const* d_in, const int* in_sizes, int n_in,
                              void* d_out, int out_size, void* d_ws, size_t ws_size,
                              hipStream_t stream) {
    const float* x    = (const float*)d_in[0];
    const float* beta = (const float*)d_in[1];
    const float* con  = (const float*)d_in[2];
    const int*   ei   = (const int*)d_in[3];

    int N = in_sizes[0] / D;
    int E = in_sizes[3] / 2;
    const int* row_idx = ei;
    const int* col_idx = ei + E;

    float* out = (float*)d_out;
    float* sn     = (float*)d_ws;           // N floats
    float* f      = sn + N;                 // N floats
    float* rowsum = f + N;                  // N floats

    // support accumulates directly in d_out; must be zeroed (harness poisons 0xAA)
    hipMemsetAsync(d_out, 0, (size_t)N * D * sizeof(float), stream);

    int nodeBlocks = (N + 3) / 4;
    prep_kernel<<<nodeBlocks, 256, 0, stream>>>(x, sn, f, rowsum, N);

    int edgeBlocks = (E + 3) / 4;
    edge_kernel<<<edgeBlocks, 256, 0, stream>>>(x, sn, f, row_idx, col_idx,
                                                beta, con, out, rowsum, E);

    final_kernel<<<nodeBlocks, 256, 0, stream>>>(out, rowsum, N);
}